// Round 12
// baseline (453.732 us; speedup 1.0000x reference)
//
#include <hip/hip_runtime.h>
#include <math.h>

static constexpr int BB  = 4;
static constexpr int S   = 2048;
static constexpr int D   = 512;
static constexpr int DFF = 2048;
static constexpr int BS  = BB * S;   // 8192 rows

using v8h = __attribute__((ext_vector_type(8))) _Float16;
using v4h = __attribute__((ext_vector_type(4))) _Float16;
using v2h = __attribute__((ext_vector_type(2))) _Float16;
using v4f = __attribute__((ext_vector_type(4))) float;

// async global->LDS, 16 B per lane; LDS dest = wave-uniform base + lane*16
__device__ __forceinline__ void async16(const void* g, void* l) {
  __builtin_amdgcn_global_load_lds(
      (const __attribute__((address_space(1))) unsigned int*)g,
      (__attribute__((address_space(3))) unsigned int*)l, 16, 0, 0);
}

// ---- XCD-aware bijective block swizzle (T1). Requires nwg % 8 == 0. ----
__device__ __forceinline__ void xcd_swizzle(int& bx, int& by) {
  const int nx = gridDim.x;
  const int nwg = nx * gridDim.y;
  const int lin = by * nx + bx;
  const int q = nwg >> 3;
  const int nl = (lin & 7) * q + (lin >> 3);
  bx = nl % nx;
  by = nl / nx;
}

// ---- fast GELU: exact-erf form with inline A&S 7.1.26 erf (max err 1.5e-7).
__device__ __forceinline__ float fast_gelu(float v) {
  const float u = 0.7071067811865476f * v;
  const float a = fabsf(u);
  const float t = 1.0f / (1.0f + 0.3275911f * a);
  const float p =
      t * (0.254829592f +
           t * (-0.284496736f +
                t * (1.421413741f + t * (-1.453152027f + t * 1.061405429f))));
  const float e = exp2f(-u * u * 1.4426950408889634f);
  const float erfv = copysignf(1.0f - p * e, u);
  return 0.5f * v * (1.0f + erfv);
}

// ---- block-wide reductions (block = 256 threads = 4 waves) ----
__device__ __forceinline__ float blockSum(float v) {
#pragma unroll
  for (int o = 32; o; o >>= 1) v += __shfl_xor(v, o, 64);
  __shared__ float t[4];
  __syncthreads();
  if ((threadIdx.x & 63) == 0) t[threadIdx.x >> 6] = v;
  __syncthreads();
  return t[0] + t[1] + t[2] + t[3];
}
__device__ __forceinline__ float blockMax(float v) {
#pragma unroll
  for (int o = 32; o; o >>= 1) v = fmaxf(v, __shfl_xor(v, o, 64));
  __shared__ float t[4];
  __syncthreads();
  if ((threadIdx.x & 63) == 0) t[threadIdx.x >> 6] = v;
  __syncthreads();
  return fmaxf(fmaxf(t[0], t[1]), fmaxf(t[2], t[3]));
}

// ---- embedding gather + positional encoding (fp32 math); fp32 + fp16 copy ----
__global__ __launch_bounds__(256) void embed_pos_k(
    const int* __restrict__ seq, const float* __restrict__ emb,
    float* __restrict__ X, _Float16* __restrict__ Xh) {
  const int bs = blockIdx.x;
  const int s  = bs & (S - 1);
  const int idx = seq[bs];
  const float* er = emb + (size_t)idx * D;
  const float cexp = -0.05190512648261504f;
  const int d0 = threadIdx.x * 2;
  const float2 e2 = *(const float2*)&er[d0];
  const float a0 = (float)s * exp2f((float)d0 * cexp);
  const float a1 = (float)s * exp2f((float)(d0 + 1) * cexp);
  const float v0 = (e2.x + sinf(a0)) * 22.62741699796952f;  // * sqrt(512)
  const float v1 = (e2.y + cosf(a1)) * 22.62741699796952f;
  const size_t o = (size_t)bs * D + d0;
  *(float2*)&X[o] = make_float2(v0, v1);
  *(v2h*)&Xh[o] = v2h{(_Float16)v0, (_Float16)v1};
}

// ---- one-shot weight prep: transposed fp16 copies + concatenated qkv ----
__global__ __launch_bounds__(256) void prep_k(
    const float* __restrict__ wk, const float* __restrict__ wq,
    const float* __restrict__ wv, const float* __restrict__ w1,
    const float* __restrict__ w2, const float* __restrict__ bk,
    const float* __restrict__ bq, const float* __restrict__ bv,
    _Float16* __restrict__ wcat, _Float16* __restrict__ w1T,
    _Float16* __restrict__ w2T, float* __restrict__ bcat) {
  const int idx = blockIdx.x * 256 + threadIdx.x;
  if (idx < 786432) {                 // 3 x 512x512
    const int which = idx >> 18, e = idx & 262143;
    const int k = e >> 9, n = e & 511;
    const float* w = (which == 0) ? wk : (which == 1) ? wq : wv;
    wcat[((long)(which * 512 + n)) * 512 + k] = (_Float16)w[e];
  } else if (idx < 786432 + 1048576) {  // w1 [512][2048]
    const int e = idx - 786432;
    const int k = e >> 11, n = e & 2047;
    w1T[(long)n * 512 + k] = (_Float16)w1[e];
  } else if (idx < 786432 + 2097152) {  // w2 [2048][512]
    const int e = idx - 786432 - 1048576;
    const int k = e >> 9, n = e & 511;
    w2T[(long)n * 2048 + k] = (_Float16)w2[e];
  } else if (idx < 786432 + 2097152 + 1536) {
    const int e = idx - 786432 - 2097152;
    const float* b = (e < 512) ? bk : (e < 1024) ? bq : bv;
    bcat[e] = b[e & 511];
  }
}

// ============================================================================
// BK=32 MFMA GEMM: 128x128 tile, 32 KB LDS (R10-verified).
// ============================================================================
template <int OMODE, int ACT>
__global__ __launch_bounds__(256) void mm32_k(
    const _Float16* __restrict__ Ap, const _Float16* __restrict__ Bp,
    void* __restrict__ Cp, void* __restrict__ Cp2, void* __restrict__ Cp3,
    const float* __restrict__ bias,
    int N, int K, long sA, long sB, long sC, float scale) {
  constexpr int ATE = 128 * 32;      // 4096 elems, 8 KB
  constexpr int TILE = 2 * ATE;      // A + B, 16 KB
  __shared__ __align__(16) _Float16 lds[2 * TILE];  // 32 KB double-buffered

  const int tid = threadIdx.x, lane = tid & 63, w = tid >> 6;
  const int quad = lane >> 4, l16 = lane & 15;
  const int wm = w >> 1, wn = w & 1;     // 2x2 wave grid, 64x64 out each
  int bx = blockIdx.x, by = blockIdx.y;
  xcd_swizzle(bx, by);
  const int m0 = by * 128, n0 = bx * 128;

  const _Float16* A = Ap + (long)blockIdx.z * sA;
  const _Float16* B = Bp + (long)blockIdx.z * sB;

  v4f acc[4][4] = {};
  const int rloc = lane >> 2;                       // row within 16-row group
  const int cs = (lane & 3) ^ ((rloc >> 1) & 3);    // pre-swizzled src chunk

  auto stage = [&](int k0, int half) {
    _Float16* Ah = lds + half * TILE;
    _Float16* Bh = Ah + ATE;
#pragma unroll
    for (int i = 0; i < 2; ++i) {
      const int is = w + i * 4;                     // 0..7, 16 rows each
      async16(A + (long)(m0 + is * 16 + rloc) * K + k0 + cs * 8, Ah + is * 512);
      async16(B + (long)(n0 + is * 16 + rloc) * K + k0 + cs * 8, Bh + is * 512);
    }
  };

  stage(0, 0);
  __syncthreads();  // tile 0 landed

  const int nK = K >> 5;
  for (int t = 0; t < nK; ++t) {
    const int cur = t & 1;
    if (t + 1 < nK) stage((t + 1) << 5, cur ^ 1);  // prefetch next tile

    const _Float16* Ah = lds + cur * TILE;
    const _Float16* Bh = Ah + ATE;

    v8h af[4], bfr[4];
#pragma unroll
    for (int mt = 0; mt < 4; ++mt) {
      const int rr = wm * 64 + mt * 16 + l16;
      const int pc = quad ^ ((rr >> 1) & 3);
      af[mt] = *(v8h*)&Ah[rr * 32 + pc * 8];
    }
#pragma unroll
    for (int nt = 0; nt < 4; ++nt) {
      const int rn = wn * 64 + nt * 16 + l16;
      const int pc = quad ^ ((rn >> 1) & 3);
      bfr[nt] = *(v8h*)&Bh[rn * 32 + pc * 8];
    }
#pragma unroll
    for (int mt = 0; mt < 4; ++mt)
#pragma unroll
      for (int nt = 0; nt < 4; ++nt)
        acc[mt][nt] = __builtin_amdgcn_mfma_f32_16x16x32_f16(
            af[mt], bfr[nt], acc[mt][nt], 0, 0, 0);

    __syncthreads();  // drains vmcnt(0): tile t+1 ready; buffer cur free
  }

  // ---- epilogue (C layout: col = lane&15, row = quad*4 + reg) ----
  const long Cz = (long)blockIdx.z * sC;
  const int region = n0 >> 9;          // block-uniform (OMODE 4)
#pragma unroll
  for (int nt = 0; nt < 4; ++nt) {
    const int gn = n0 + wn * 64 + nt * 16 + l16;
    const int gnl = gn & 511;
    const float bv = bias ? bias[gn] : 0.0f;
#pragma unroll
    for (int mt = 0; mt < 4; ++mt) {
      const int gmb = m0 + wm * 64 + mt * 16 + quad * 4;
      if constexpr (OMODE == 4) {
        if (region == 2) {  // vT[z][gnl][m] — 4 consecutive m: one 8B store
          const int z2 = gmb >> 11, ml = gmb & 2047;
          v4h h4;
#pragma unroll
          for (int r = 0; r < 4; ++r)
            h4[r] = (_Float16)(acc[mt][nt][r] * scale + bv);
          *(v4h*)&((_Float16*)Cp3)[((long)z2 * 512 + gnl) * 2048 + ml] = h4;
          continue;
        }
      }
#pragma unroll
      for (int r = 0; r < 4; ++r) {
        const int gm = gmb + r;
        float v = acc[mt][nt][r] * scale + bv;
        if constexpr (ACT == 1) v = fast_gelu(v);
        if constexpr (OMODE == 1) {
          ((_Float16*)Cp)[Cz + (long)gm * N + gn] = (_Float16)v;
        } else if constexpr (OMODE == 4) {
          if (region == 0) {
            ((_Float16*)Cp)[(long)gm * 512 + gnl] = (_Float16)v;
          } else {
            ((_Float16*)Cp2)[(long)gm * 512 + gnl] = (_Float16)v;
          }
        } else {
          ((float*)Cp)[Cz + (long)gm * N + gn] = v;
        }
      }
    }
  }
}

// ============================================================================
// Fused online-softmax + PV GEMM (replaces softmax_k + plain PV).
// attn[i,:] = softmax(Sc[i,:]) @ vT^T. Built on the R5/R9-verified mm64p
// skeleton (3 LDS buffers, 2-deep prefetch, counted vmcnt(12)).
// A = RAW logits (scores GEMM output, already scaled 1/sqrt(D)).
// Race/hang audit in session journal (R11): uniform barriers; vmcnt waits
// terminate; rS/mS step-t reads separated from step-t+1 writes by barriers
// A+B; lgkmcnt(0)+barrier publishes before all-wave reads; single writer
// (wave0/quad0) for mS/lS/rS; row extent = 16 in-thread x 4 quads via
// shfl_xor(16,32); elementwise exp preserves MFMA A-fragment layout.
// ============================================================================
__global__ __launch_bounds__(256) void pv_sm_k(
    const _Float16* __restrict__ Ap, const _Float16* __restrict__ Bp,
    float* __restrict__ Cp,
    int N, int K, long sA, long sB, long sC) {
  constexpr int ATE = 64 * 64;       // 8 KB
  constexpr int BTE = 128 * 64;      // 16 KB
  constexpr int TILE = ATE + BTE;    // 24 KB
  __shared__ __align__(16) _Float16 lds[3 * TILE];
  __shared__ __align__(16) float mS[64], lS[64], rS[64];

  const int tid = threadIdx.x, lane = tid & 63, w = tid >> 6;
  const int quad = lane >> 4, l16 = lane & 15;
  int bx = blockIdx.x, by = blockIdx.y;
  xcd_swizzle(bx, by);
  const int m0 = by * 64, n0 = bx * 128;

  const _Float16* A = Ap + (long)blockIdx.z * sA;
  const _Float16* B = Bp + (long)blockIdx.z * sB;

  if (tid < 64) { mS[tid] = -1e30f; lS[tid] = 0.0f; }

  v4f acc[4][2] = {};
  const int srow8 = lane >> 3;
  const int cs = (lane & 7) ^ srow8;
  const int lsw = l16 & 7;
  const float L2E = 1.44269504f;

  auto stage = [&](int t) {
    _Float16* Ah = lds + (t % 3) * TILE;
    _Float16* Bh = Ah + ATE;
    const int k0 = t << 6;
#pragma unroll
    for (int i = 0; i < 2; ++i) {
      const int is = w + i * 4;
      async16(A + (long)(m0 + is * 8 + srow8) * K + k0 + cs * 8, Ah + is * 512);
    }
#pragma unroll
    for (int i = 0; i < 4; ++i) {
      const int is = w + i * 4;
      async16(B + (long)(n0 + is * 8 + srow8) * K + k0 + cs * 8, Bh + is * 512);
    }
  };

  const int nK = K >> 6;          // 32
  stage(0);
  stage(1);

  for (int t = 0; t < nK; ++t) {
    __builtin_amdgcn_s_barrier();  // (A) everyone done reading buf[(t+2)%3]
    if (t + 2 < nK) {
      stage(t + 2);
      asm volatile("s_waitcnt vmcnt(12)" ::: "memory");  // tile t landed
    } else if (t + 1 < nK) {
      asm volatile("s_waitcnt vmcnt(6)" ::: "memory");
    } else {
      asm volatile("s_waitcnt vmcnt(0)" ::: "memory");
    }
    __builtin_amdgcn_s_barrier();  // (B) tile t fully in LDS (all waves)

    const _Float16* Ah = lds + (t % 3) * TILE;
    const _Float16* Bh = Ah + ATE;

    v8h af[4][2], bfr[2][2];
#pragma unroll
    for (int mt = 0; mt < 4; ++mt) {
      const int rr = mt * 16 + l16;
#pragma unroll
      for (int kk = 0; kk < 2; ++kk) {
        const int c = (kk * 4 + quad) ^ lsw;
        af[mt][kk] = *(v8h*)&Ah[rr * 64 + c * 8];
      }
    }
#pragma unroll
    for (int nt = 0; nt < 2; ++nt) {
      const int rn = w * 32 + nt * 16 + l16;
#pragma unroll
      for (int kk = 0; kk < 2; ++kk) {
        const int c = (kk * 4 + quad) ^ lsw;
        bfr[nt][kk] = *(v8h*)&Bh[rn * 64 + c * 8];
      }
    }

    // ---- online softmax: tile row-max (row rr = mt*16+l16) ----
    float tmax[4];
#pragma unroll
    for (int mt = 0; mt < 4; ++mt) {
      float tm = -1e30f;
#pragma unroll
      for (int kk = 0; kk < 2; ++kk)
#pragma unroll
        for (int j = 0; j < 8; ++j)
          tm = fmaxf(tm, (float)af[mt][kk][j]);
      tm = fmaxf(tm, __shfl_xor(tm, 16, 64));
      tm = fmaxf(tm, __shfl_xor(tm, 32, 64));
      tmax[mt] = tm;
    }
    if (w == 0 && quad == 0) {     // single writer per row
#pragma unroll
      for (int mt = 0; mt < 4; ++mt) {
        const int rr = mt * 16 + l16;
        const float mo = mS[rr];
        const float mn = fmaxf(mo, tmax[mt]);
        rS[rr] = exp2f((mo - mn) * L2E);
        mS[rr] = mn;
      }
    }
    asm volatile("s_waitcnt lgkmcnt(0)" ::: "memory");
    __builtin_amdgcn_s_barrier();  // (C) mS/rS visible to all waves

    // ---- P = exp(logit - m), fp16 fragments + row sums ----
    v8h paf[4][2];
    float ts[4];
#pragma unroll
    for (int mt = 0; mt < 4; ++mt) {
      const int rr = mt * 16 + l16;
      const float mn = mS[rr];
      float s = 0.f;
#pragma unroll
      for (int kk = 0; kk < 2; ++kk)
#pragma unroll
        for (int j = 0; j < 8; ++j) {
          const float p = exp2f(((float)af[mt][kk][j] - mn) * L2E);
          s += p;
          paf[mt][kk][j] = (_Float16)p;
        }
      s += __shfl_xor(s, 16, 64);
      s += __shfl_xor(s, 32, 64);
      ts[mt] = s;
    }
    if (w == 0 && quad == 0) {
#pragma unroll
      for (int mt = 0; mt < 4; ++mt) {
        const int rr = mt * 16 + l16;
        lS[rr] = lS[rr] * rS[rr] + ts[mt];
      }
    }

    // ---- rescale acc (rows = mt*16 + quad*4 + r) ----
#pragma unroll
    for (int mt = 0; mt < 4; ++mt) {
      const v4f r4 = *(const v4f*)&rS[mt * 16 + quad * 4];
#pragma unroll
      for (int nt = 0; nt < 2; ++nt)
#pragma unroll
        for (int r = 0; r < 4; ++r)
          acc[mt][nt][r] *= r4[r];
    }

    // ---- PV MFMA ----
#pragma unroll
    for (int kk = 0; kk < 2; ++kk)
#pragma unroll
      for (int mt = 0; mt < 4; ++mt)
#pragma unroll
        for (int nt = 0; nt < 2; ++nt)
          acc[mt][nt] = __builtin_amdgcn_mfma_f32_16x16x32_f16(
              paf[mt][kk], bfr[nt][kk], acc[mt][nt], 0, 0, 0);
  }

  asm volatile("s_waitcnt lgkmcnt(0)" ::: "memory");
  __builtin_amdgcn_s_barrier();    // lS final values visible

  // ---- epilogue: divide by row sums ----
  const long Cz = (long)blockIdx.z * sC;
#pragma unroll
  for (int nt = 0; nt < 2; ++nt) {
    const int gn = n0 + w * 32 + nt * 16 + l16;
#pragma unroll
    for (int mt = 0; mt < 4; ++mt) {
      const int gmb = m0 + mt * 16 + quad * 4;
      const v4f l4 = *(const v4f*)&lS[mt * 16 + quad * 4];
#pragma unroll
      for (int r = 0; r < 4; ++r)
        Cp[Cz + (long)(gmb + r) * N + gn] = acc[mt][nt][r] / l4[r];
    }
  }
}

// ============================================================================
// TM=64 pipelined GEMM (FF2: K=2048, N=512). R5/R9-verified form:
// 3 LDS buffers, 2-deep prefetch, counted vmcnt(12).
// ============================================================================
__global__ __launch_bounds__(256) void mm64p_k(
    const _Float16* __restrict__ Ap, const _Float16* __restrict__ Bp,
    float* __restrict__ Cp, const float* __restrict__ bias,
    int N, int K, long sA, long sB, long sC, float scale) {
  constexpr int ATE = 64 * 64;       // 8 KB
  constexpr int BTE = 128 * 64;      // 16 KB
  constexpr int TILE = ATE + BTE;    // 24 KB
  __shared__ __align__(16) _Float16 lds[3 * TILE];

  const int tid = threadIdx.x, lane = tid & 63, w = tid >> 6;
  const int quad = lane >> 4, l16 = lane & 15;
  int bx = blockIdx.x, by = blockIdx.y;
  xcd_swizzle(bx, by);
  const int m0 = by * 64, n0 = bx * 128;

  const _Float16* A = Ap + (long)blockIdx.z * sA;
  const _Float16* B = Bp + (long)blockIdx.z * sB;

  v4f acc[4][2] = {};
  const int srow8 = lane >> 3;
  const int cs = (lane & 7) ^ srow8;
  const int lsw = l16 & 7;

  auto stage = [&](int t) {
    _Float16* Ah = lds + (t % 3) * TILE;
    _Float16* Bh = Ah + ATE;
    const int k0 = t << 6;
#pragma unroll
    for (int i = 0; i < 2; ++i) {
      const int is = w + i * 4;
      async16(A + (long)(m0 + is * 8 + srow8) * K + k0 + cs * 8, Ah + is * 512);
    }
#pragma unroll
    for (int i = 0; i < 4; ++i) {
      const int is = w + i * 4;
      async16(B + (long)(n0 + is * 8 + srow8) * K + k0 + cs * 8, Bh + is * 512);
    }
  };

  const int nK = K >> 6;          // 32 for all uses
  stage(0);
  stage(1);

  for (int t = 0; t < nK; ++t) {
    __builtin_amdgcn_s_barrier();  // (A) everyone done reading buf[(t+2)%3]
    if (t + 2 < nK) {
      stage(t + 2);
      asm volatile("s_waitcnt vmcnt(12)" ::: "memory");  // tile t landed
    } else if (t + 1 < nK) {
      asm volatile("s_waitcnt vmcnt(6)" ::: "memory");
    } else {
      asm volatile("s_waitcnt vmcnt(0)" ::: "memory");
    }
    __builtin_amdgcn_s_barrier();  // (B) tile t fully in LDS (all waves)

    const _Float16* Ah = lds + (t % 3) * TILE;
    const _Float16* Bh = Ah + ATE;

    v8h af[4][2], bfr[2][2];
#pragma unroll
    for (int mt = 0; mt < 4; ++mt) {
      const int rr = mt * 16 + l16;
#pragma unroll
      for (int kk = 0; kk < 2; ++kk) {
        const int c = (kk * 4 + quad) ^ lsw;
        af[mt][kk] = *(v8h*)&Ah[rr * 64 + c * 8];
      }
    }
#pragma unroll
    for (int nt = 0; nt < 2; ++nt) {
      const int rn = w * 32 + nt * 16 + l16;
#pragma unroll
      for (int kk = 0; kk < 2; ++kk) {
        const int c = (kk * 4 + quad) ^ lsw;
        bfr[nt][kk] = *(v8h*)&Bh[rn * 64 + c * 8];
      }
    }
#pragma unroll
    for (int kk = 0; kk < 2; ++kk)
#pragma unroll
      for (int mt = 0; mt < 4; ++mt)
#pragma unroll
        for (int nt = 0; nt < 2; ++nt)
          acc[mt][nt] = __builtin_amdgcn_mfma_f32_16x16x32_f16(
              af[mt][kk], bfr[nt][kk], acc[mt][nt], 0, 0, 0);
  }

  // ---- epilogue (fp32 out) ----
  const long Cz = (long)blockIdx.z * sC;
#pragma unroll
  for (int nt = 0; nt < 2; ++nt) {
    const int gn = n0 + w * 32 + nt * 16 + l16;
    const float bv = bias ? bias[gn] : 0.0f;
#pragma unroll
    for (int mt = 0; mt < 4; ++mt) {
      const int gmb = m0 + mt * 16 + quad * 4;
#pragma unroll
      for (int r = 0; r < 4; ++r) {
        const int gm = gmb + r;
        Cp[Cz + (long)gm * N + gn] = acc[mt][nt][r] * scale + bv;
      }
    }
  }
}

// ---- r = LayerNorm(X + Add) -> X (in place) + fp16 copy rF ----
__global__ __launch_bounds__(256) void ln_res_k(
    float* __restrict__ X, const float* __restrict__ Add,
    const float* __restrict__ g, const float* __restrict__ b,
    _Float16* __restrict__ rF) {
  float* xr = X + (size_t)blockIdx.x * D;
  const float* ar = Add + (size_t)blockIdx.x * D;
  _Float16* rf = rF + (size_t)blockIdx.x * D;
  const int d0 = threadIdx.x * 2;
  const float2 xv = *(const float2*)&xr[d0];
  const float2 av = *(const float2*)&ar[d0];
  const float z0 = xv.x + av.x;
  const float z1 = xv.y + av.y;
  const float mu = blockSum(z0 + z1) * (1.0f / D);
  const float dd0 = z0 - mu, dd1 = z1 - mu;
  const float var = blockSum(dd0 * dd0 + dd1 * dd1) * (1.0f / D);
  const float rs = rsqrtf(var + 1e-5f);
  const float2 gv = *(const float2*)&g[d0];
  const float2 bv = *(const float2*)&b[d0];
  const float v0 = dd0 * rs * gv.x + bv.x;
  const float v1 = dd1 * rs * gv.y + bv.y;
  *(float2*)&xr[d0] = make_float2(v0, v1);
  *(v2h*)&rf[d0] = v2h{(_Float16)v0, (_Float16)v1};
}

// ---- out = LayerNorm(R + F), fp32 ----
__global__ __launch_bounds__(256) void ln_out_k(
    const float* __restrict__ R, const float* __restrict__ F,
    const float* __restrict__ g, const float* __restrict__ b,
    float* __restrict__ out) {
  const float* rr = R + (size_t)blockIdx.x * D;
  const float* fr = F + (size_t)blockIdx.x * D;
  float* orow = out + (size_t)blockIdx.x * D;
  const int d0 = threadIdx.x * 2;
  const float2 rv = *(const float2*)&rr[d0];
  const float2 fv = *(const float2*)&fr[d0];
  const float z0 = rv.x + fv.x;
  const float z1 = rv.y + fv.y;
  const float mu = blockSum(z0 + z1) * (1.0f / D);
  const float dd0 = z0 - mu, dd1 = z1 - mu;
  const float var = blockSum(dd0 * dd0 + dd1 * dd1) * (1.0f / D);
  const float rs = rsqrtf(var + 1e-5f);
  const float2 gv = *(const float2*)&g[d0];
  const float2 bv = *(const float2*)&b[d0];
  *(float2*)&orow[d0] =
      make_float2(dd0 * rs * gv.x + bv.x, dd1 * rs * gv.y + bv.y);
}

extern "C" void kernel_launch(void* const* d_in, const int* in_sizes, int n_in,
                              void* d_out, int out_size, void* d_ws, size_t ws_size,
                              hipStream_t stream) {
  (void)in_sizes; (void)n_in; (void)out_size; (void)ws_size;
  const int*   seq = (const int*)d_in[0];
  const float* emb = (const float*)d_in[1];
  const float* wk  = (const float*)d_in[2];
  const float* bk  = (const float*)d_in[3];
  const float* wq  = (const float*)d_in[4];
  const float* bq  = (const float*)d_in[5];
  const float* wv  = (const float*)d_in[6];
  const float* bv  = (const float*)d_in[7];
  const float* lng = (const float*)d_in[8];
  const float* lnb = (const float*)d_in[9];
  const float* w1  = (const float*)d_in[10];
  const float* b1  = (const float*)d_in[11];
  const float* w2  = (const float*)d_in[12];
  const float* b2  = (const float*)d_in[13];

  // Workspace (MB offsets, lifetimes):
  //  [0,16)    X fp32 (x -> r in-place)
  //  [16,24)   Xh fp16 (dead after QKV)
  //  [24,32)   kF fp16 (dead after scores)  -> rF fp16
  //  [32,40)   qF fp16 (dead after scores)  -> ff fp32 [32,48)
  //  [40,48)   vT fp16 [z][D][S]            (ff tail; vT dead after PV)
  //  [48,80)   Sc fp16 RAW logits (dead after pv_sm) -> hF fp16
  //  [81,97)   attn fp32 (dead after ln_res)
  //  [100,...) wcat 1.5MB, bcat 8KB, w1T 2MB, w2T 2MB
  const size_t MBy = 1024 * 1024;
  char* wsb = (char*)d_ws;
  float*    X    = (float*)wsb;
  _Float16* Xh   = (_Float16*)(wsb + 16 * MBy);
  _Float16* kF   = (_Float16*)(wsb + 24 * MBy);
  _Float16* qF   = (_Float16*)(wsb + 32 * MBy);
  _Float16* vT   = (_Float16*)(wsb + 40 * MBy);
  _Float16* Sc   = (_Float16*)(wsb + 48 * MBy);
  float*    attn = (float*)(wsb + 81 * MBy);
  _Float16* rF   = (_Float16*)(wsb + 24 * MBy);
  _Float16* hF   = (_Float16*)(wsb + 48 * MBy);
  float*    ff   = (float*)(wsb + 32 * MBy);
  _Float16* wcat = (_Float16*)(wsb + 100 * MBy);
  float*    bcat = (float*)(wsb + 102 * MBy);
  _Float16* w1T  = (_Float16*)(wsb + 103 * MBy);
  _Float16* w2T  = (_Float16*)(wsb + 105 * MBy);

  const long SD = (long)S * D, SSl = (long)S * S;

  prep_k<<<11270, 256, 0, stream>>>(wk, wq, wv, w1, w2, bk, bq, bv,
                                    wcat, w1T, w2T, bcat);
  embed_pos_k<<<BS, 256, 0, stream>>>(seq, emb, X, Xh);

  // fused QKV projection: [8192,512] @ wcat^T[512,1536] (BK=32)
  mm32_k<4, 0><<<dim3(12, 64, 1), 256, 0, stream>>>(
      Xh, wcat, kF, qF, vT, bcat, 1536, D, 0, 0, 0, 1.0f);

  // scores = (k @ q^T)/sqrt(D) -> fp16 RAW logits, batched (BK=32)
  mm32_k<1, 0><<<dim3(16, 16, BB), 256, 0, stream>>>(
      kF, qF, Sc, nullptr, nullptr, nullptr, S, D, SD, SD, SSl,
      0.044194173824159216f);

  // attn = softmax(Sc) @ v — fused online-softmax PV, batched
  pv_sm_k<<<dim3(4, 32, BB), 256, 0, stream>>>(
      Sc, vT, attn, D, S, SSl, (long)D * S, SD);

  // r = LN(x + attn) -> X (+ fp16 rF)
  ln_res_k<<<BS, 256, 0, stream>>>(X, attn, lng, lnb, rF);

  // h = gelu(r @ w1 + b1) -> fp16 (BK=32, fast inline erf)
  mm32_k<1, 1><<<dim3(16, 64, 1), 256, 0, stream>>>(
      rF, w1T, hF, nullptr, nullptr, b1, DFF, D, 0, 0, 0, 1.0f);
  // ff = h @ w2 + b2 -> fp32 (pipelined TM=64, 3-buf 2-deep)
  mm64p_k<<<dim3(4, 128, 1), 256, 0, stream>>>(
      hF, w2T, ff, b2, D, DFF, 0, 0, 0, 1.0f);

  // out = LN(r + ff)
  ln_out_k<<<BS, 256, 0, stream>>>(X, ff, lng, lnb, (float*)d_out);
}

// Round 13
// 339.593 us; speedup vs baseline: 1.3361x; 1.3361x over previous
//
#include <hip/hip_runtime.h>
#include <math.h>

static constexpr int BB  = 4;
static constexpr int S   = 2048;
static constexpr int D   = 512;
static constexpr int DFF = 2048;
static constexpr int BS  = BB * S;   // 8192 rows

using v8h = __attribute__((ext_vector_type(8))) _Float16;
using v4h = __attribute__((ext_vector_type(4))) _Float16;
using v2h = __attribute__((ext_vector_type(2))) _Float16;
using v4f = __attribute__((ext_vector_type(4))) float;

// async global->LDS, 16 B per lane; LDS dest = wave-uniform base + lane*16
__device__ __forceinline__ void async16(const void* g, void* l) {
  __builtin_amdgcn_global_load_lds(
      (const __attribute__((address_space(1))) unsigned int*)g,
      (__attribute__((address_space(3))) unsigned int*)l, 16, 0, 0);
}

// ---- XCD-aware bijective block swizzle (T1). Requires nwg % 8 == 0. ----
__device__ __forceinline__ void xcd_swizzle(int& bx, int& by) {
  const int nx = gridDim.x;
  const int nwg = nx * gridDim.y;
  const int lin = by * nx + bx;
  const int q = nwg >> 3;
  const int nl = (lin & 7) * q + (lin >> 3);
  bx = nl % nx;
  by = nl / nx;
}

// ---- fast GELU: exact-erf form with inline A&S 7.1.26 erf (max err 1.5e-7).
// R8-verified: passed, absmax unchanged.
__device__ __forceinline__ float fast_gelu(float v) {
  const float u = 0.7071067811865476f * v;
  const float a = fabsf(u);
  const float t = 1.0f / (1.0f + 0.3275911f * a);
  const float p =
      t * (0.254829592f +
           t * (-0.284496736f +
                t * (1.421413741f + t * (-1.453152027f + t * 1.061405429f))));
  const float e = exp2f(-u * u * 1.4426950408889634f);
  const float erfv = copysignf(1.0f - p * e, u);
  return 0.5f * v * (1.0f + erfv);
}

// ---- block-wide reductions (block = 256 threads = 4 waves) ----
__device__ __forceinline__ float blockSum(float v) {
#pragma unroll
  for (int o = 32; o; o >>= 1) v += __shfl_xor(v, o, 64);
  __shared__ float t[4];
  __syncthreads();
  if ((threadIdx.x & 63) == 0) t[threadIdx.x >> 6] = v;
  __syncthreads();
  return t[0] + t[1] + t[2] + t[3];
}
__device__ __forceinline__ float blockMax(float v) {
#pragma unroll
  for (int o = 32; o; o >>= 1) v = fmaxf(v, __shfl_xor(v, o, 64));
  __shared__ float t[4];
  __syncthreads();
  if ((threadIdx.x & 63) == 0) t[threadIdx.x >> 6] = v;
  __syncthreads();
  return fmaxf(fmaxf(t[0], t[1]), fmaxf(t[2], t[3]));
}

// ---- embedding gather + positional encoding (fp32 math); fp32 + fp16 copy ----
__global__ __launch_bounds__(256) void embed_pos_k(
    const int* __restrict__ seq, const float* __restrict__ emb,
    float* __restrict__ X, _Float16* __restrict__ Xh) {
  const int bs = blockIdx.x;
  const int s  = bs & (S - 1);
  const int idx = seq[bs];
  const float* er = emb + (size_t)idx * D;
  const float cexp = -0.05190512648261504f;
  const int d0 = threadIdx.x * 2;
  const float2 e2 = *(const float2*)&er[d0];
  const float a0 = (float)s * exp2f((float)d0 * cexp);
  const float a1 = (float)s * exp2f((float)(d0 + 1) * cexp);
  const float v0 = (e2.x + sinf(a0)) * 22.62741699796952f;  // * sqrt(512)
  const float v1 = (e2.y + cosf(a1)) * 22.62741699796952f;
  const size_t o = (size_t)bs * D + d0;
  *(float2*)&X[o] = make_float2(v0, v1);
  *(v2h*)&Xh[o] = v2h{(_Float16)v0, (_Float16)v1};
}

// ---- one-shot weight prep: transposed fp16 copies + concatenated qkv ----
__global__ __launch_bounds__(256) void prep_k(
    const float* __restrict__ wk, const float* __restrict__ wq,
    const float* __restrict__ wv, const float* __restrict__ w1,
    const float* __restrict__ w2, const float* __restrict__ bk,
    const float* __restrict__ bq, const float* __restrict__ bv,
    _Float16* __restrict__ wcat, _Float16* __restrict__ w1T,
    _Float16* __restrict__ w2T, float* __restrict__ bcat) {
  const int idx = blockIdx.x * 256 + threadIdx.x;
  if (idx < 786432) {                 // 3 x 512x512
    const int which = idx >> 18, e = idx & 262143;
    const int k = e >> 9, n = e & 511;
    const float* w = (which == 0) ? wk : (which == 1) ? wq : wv;
    wcat[((long)(which * 512 + n)) * 512 + k] = (_Float16)w[e];
  } else if (idx < 786432 + 1048576) {  // w1 [512][2048]
    const int e = idx - 786432;
    const int k = e >> 11, n = e & 2047;
    w1T[(long)n * 512 + k] = (_Float16)w1[e];
  } else if (idx < 786432 + 2097152) {  // w2 [2048][512]
    const int e = idx - 786432 - 1048576;
    const int k = e >> 9, n = e & 511;
    w2T[(long)n * 2048 + k] = (_Float16)w2[e];
  } else if (idx < 786432 + 2097152 + 1536) {
    const int e = idx - 786432 - 2097152;
    const float* b = (e < 512) ? bk : (e < 1024) ? bq : bv;
    bcat[e] = b[e & 511];
  }
}

// ---- MFMA GEMM: C = act(scale * A @ B^T + bias), fp16 in, fp32 acc ----
// A[M,K], B[N,K] row-major fp16. Tile TMx128, BK=64.
// OMODE: 0 = fp32, 1 = fp16, 4 = fused-QKV split: region = n0>>9
// Staging: global_load_lds w16; XOR swizzle chunk^=(row&7) (conflict-free).
// 2-phase prefetch double-buffer; one __syncthreads per k-step.
// Session laws: >= 2 blocks/CU required (R2/R3/R6); short compute phases
// need 2-deep prefetch (R8); VALU work must stay OUT of the k-loop (R12).
template <int TM, int OMODE, int ACT>
__global__ __launch_bounds__(256) void mm_k(
    const _Float16* __restrict__ Ap, const _Float16* __restrict__ Bp,
    void* __restrict__ Cp, void* __restrict__ Cp2, void* __restrict__ Cp3,
    const float* __restrict__ bias,
    int N, int K, long sA, long sB, long sC, float scale) {
  constexpr int ATE = TM * 64;
  constexpr int BTE = 128 * 64;
  constexpr int TILE = ATE + BTE;
  __shared__ __align__(16) _Float16 lds[2 * TILE];

  const int tid = threadIdx.x, lane = tid & 63, w = tid >> 6;
  const int quad = lane >> 4, l16 = lane & 15;
  constexpr int MT = 4;
  constexpr int NT = (TM == 128) ? 4 : 2;
  constexpr int WN = (TM == 128) ? 64 : 32;
  const int wm = (TM == 128) ? (w >> 1) : 0;
  const int wn = (TM == 128) ? (w & 1) : w;
  int bx = blockIdx.x, by = blockIdx.y;
  xcd_swizzle(bx, by);
  const int m0 = by * TM, n0 = bx * 128;

  const _Float16* A = Ap + (long)blockIdx.z * sA;
  const _Float16* B = Bp + (long)blockIdx.z * sB;

  v4f acc[MT][NT] = {};
  const int srow8 = lane >> 3;
  const int cs = (lane & 7) ^ srow8;
  const int lsw = l16 & 7;

  auto stage = [&](int k0, int half) {
    _Float16* Ah = lds + half * TILE;
    _Float16* Bh = Ah + ATE;
#pragma unroll
    for (int i = 0; i < TM / 32; ++i) {
      const int is = w + i * 4;
      async16(A + (long)(m0 + is * 8 + srow8) * K + k0 + cs * 8, Ah + is * 512);
    }
#pragma unroll
    for (int i = 0; i < 4; ++i) {
      const int is = w + i * 4;
      async16(B + (long)(n0 + is * 8 + srow8) * K + k0 + cs * 8, Bh + is * 512);
    }
  };

  stage(0, 0);
  __syncthreads();  // tile 0 landed

  const int nK = K >> 6;
  for (int t = 0; t < nK; ++t) {
    const int cur = t & 1;
    if (t + 1 < nK) stage((t + 1) << 6, cur ^ 1);  // prefetch next tile

    const _Float16* Ah = lds + cur * TILE;
    const _Float16* Bh = Ah + ATE;

    v8h af[MT][2], bfr[NT][2];
#pragma unroll
    for (int mt = 0; mt < MT; ++mt) {
      const int rr = wm * 64 + mt * 16 + l16;
#pragma unroll
      for (int kk = 0; kk < 2; ++kk) {
        const int c = (kk * 4 + quad) ^ lsw;
        af[mt][kk] = *(v8h*)&Ah[rr * 64 + c * 8];
      }
    }
#pragma unroll
    for (int nt = 0; nt < NT; ++nt) {
      const int rn = wn * WN + nt * 16 + l16;
#pragma unroll
      for (int kk = 0; kk < 2; ++kk) {
        const int c = (kk * 4 + quad) ^ lsw;
        bfr[nt][kk] = *(v8h*)&Bh[rn * 64 + c * 8];
      }
    }
#pragma unroll
    for (int kk = 0; kk < 2; ++kk)
#pragma unroll
      for (int mt = 0; mt < MT; ++mt)
#pragma unroll
        for (int nt = 0; nt < NT; ++nt)
          acc[mt][nt] = __builtin_amdgcn_mfma_f32_16x16x32_f16(
              af[mt][kk], bfr[nt][kk], acc[mt][nt], 0, 0, 0);

    __syncthreads();  // drains vmcnt(0): tile t+1 ready; buffer cur free
  }

  // ---- epilogue (C layout: col = lane&15, row = quad*4 + reg) ----
  const long Cz = (long)blockIdx.z * sC;
  const int region = n0 >> 9;          // block-uniform (OMODE 4)
#pragma unroll
  for (int nt = 0; nt < NT; ++nt) {
    const int gn = n0 + wn * WN + nt * 16 + l16;
    const int gnl = gn & 511;
    const float bv = bias ? bias[gn] : 0.0f;
#pragma unroll
    for (int mt = 0; mt < MT; ++mt) {
      const int gmb = m0 + wm * 64 + mt * 16 + quad * 4;
      if constexpr (OMODE == 4) {
        if (region == 2) {  // vT[z][gnl][m] — 4 consecutive m: one 8B store
          const int z2 = gmb >> 11, ml = gmb & 2047;
          v4h h4;
#pragma unroll
          for (int r = 0; r < 4; ++r)
            h4[r] = (_Float16)(acc[mt][nt][r] * scale + bv);
          *(v4h*)&((_Float16*)Cp3)[((long)z2 * 512 + gnl) * 2048 + ml] = h4;
          continue;
        }
      }
#pragma unroll
      for (int r = 0; r < 4; ++r) {
        const int gm = gmb + r;
        float v = acc[mt][nt][r] * scale + bv;
        if constexpr (ACT == 1) v = fast_gelu(v);
        if constexpr (OMODE == 0) {
          ((float*)Cp)[Cz + (long)gm * N + gn] = v;
        } else if constexpr (OMODE == 1) {
          ((_Float16*)Cp)[Cz + (long)gm * N + gn] = (_Float16)v;
        } else {  // OMODE 4, region 0/1
          if (region == 0) {
            ((_Float16*)Cp)[(long)gm * 512 + gnl] = (_Float16)v;
          } else {
            ((_Float16*)Cp2)[(long)gm * 512 + gnl] = (_Float16)v;
          }
        }
      }
    }
  }
}

// ============================================================================
// TM=64 pipelined GEMM (PV / FF2: K=2048, N=512). R5/R9-verified form:
// 3 LDS buffers (72 KB -> 2 blocks/CU), 2-DEEP prefetch, counted vmcnt(12).
// ============================================================================
__global__ __launch_bounds__(256) void mm64p_k(
    const _Float16* __restrict__ Ap, const _Float16* __restrict__ Bp,
    float* __restrict__ Cp, const float* __restrict__ bias,
    int N, int K, long sA, long sB, long sC, float scale) {
  constexpr int ATE = 64 * 64;       // 8 KB
  constexpr int BTE = 128 * 64;      // 16 KB
  constexpr int TILE = ATE + BTE;    // 24 KB
  __shared__ __align__(16) _Float16 lds[3 * TILE];

  const int tid = threadIdx.x, lane = tid & 63, w = tid >> 6;
  const int quad = lane >> 4, l16 = lane & 15;
  int bx = blockIdx.x, by = blockIdx.y;
  xcd_swizzle(bx, by);
  const int m0 = by * 64, n0 = bx * 128;

  const _Float16* A = Ap + (long)blockIdx.z * sA;
  const _Float16* B = Bp + (long)blockIdx.z * sB;

  v4f acc[4][2] = {};
  const int srow8 = lane >> 3;
  const int cs = (lane & 7) ^ srow8;
  const int lsw = l16 & 7;

  auto stage = [&](int t) {
    _Float16* Ah = lds + (t % 3) * TILE;
    _Float16* Bh = Ah + ATE;
    const int k0 = t << 6;
#pragma unroll
    for (int i = 0; i < 2; ++i) {
      const int is = w + i * 4;
      async16(A + (long)(m0 + is * 8 + srow8) * K + k0 + cs * 8, Ah + is * 512);
    }
#pragma unroll
    for (int i = 0; i < 4; ++i) {
      const int is = w + i * 4;
      async16(B + (long)(n0 + is * 8 + srow8) * K + k0 + cs * 8, Bh + is * 512);
    }
  };

  const int nK = K >> 6;          // 32 for all uses
  stage(0);
  stage(1);

  for (int t = 0; t < nK; ++t) {
    __builtin_amdgcn_s_barrier();  // (A) everyone done reading buf[(t+2)%3]
    if (t + 2 < nK) {
      stage(t + 2);
      asm volatile("s_waitcnt vmcnt(12)" ::: "memory");  // tile t landed
    } else if (t + 1 < nK) {
      asm volatile("s_waitcnt vmcnt(6)" ::: "memory");
    } else {
      asm volatile("s_waitcnt vmcnt(0)" ::: "memory");
    }
    __builtin_amdgcn_s_barrier();  // (B) tile t fully in LDS (all waves)

    const _Float16* Ah = lds + (t % 3) * TILE;
    const _Float16* Bh = Ah + ATE;

    v8h af[4][2], bfr[2][2];
#pragma unroll
    for (int mt = 0; mt < 4; ++mt) {
      const int rr = mt * 16 + l16;
#pragma unroll
      for (int kk = 0; kk < 2; ++kk) {
        const int c = (kk * 4 + quad) ^ lsw;
        af[mt][kk] = *(v8h*)&Ah[rr * 64 + c * 8];
      }
    }
#pragma unroll
    for (int nt = 0; nt < 2; ++nt) {
      const int rn = w * 32 + nt * 16 + l16;
#pragma unroll
      for (int kk = 0; kk < 2; ++kk) {
        const int c = (kk * 4 + quad) ^ lsw;
        bfr[nt][kk] = *(v8h*)&Bh[rn * 64 + c * 8];
      }
    }
#pragma unroll
    for (int kk = 0; kk < 2; ++kk)
#pragma unroll
      for (int mt = 0; mt < 4; ++mt)
#pragma unroll
        for (int nt = 0; nt < 2; ++nt)
          acc[mt][nt] = __builtin_amdgcn_mfma_f32_16x16x32_f16(
              af[mt][kk], bfr[nt][kk], acc[mt][nt], 0, 0, 0);
  }

  // ---- epilogue (fp32 out) ----
  const long Cz = (long)blockIdx.z * sC;
#pragma unroll
  for (int nt = 0; nt < 2; ++nt) {
    const int gn = n0 + w * 32 + nt * 16 + l16;
    const float bv = bias ? bias[gn] : 0.0f;
#pragma unroll
    for (int mt = 0; mt < 4; ++mt) {
      const int gmb = m0 + mt * 16 + quad * 4;
#pragma unroll
      for (int r = 0; r < 4; ++r) {
        const int gm = gmb + r;
        Cp[Cz + (long)gm * N + gn] = acc[mt][nt][r] * scale + bv;
      }
    }
  }
}

// ---- row softmax over S=2048 fp16 logits, in place ----
__global__ __launch_bounds__(256) void softmax_k(_Float16* __restrict__ Sc) {
  _Float16* p = Sc + (size_t)blockIdx.x * S;
  const int base = threadIdx.x * 8;
  const v8h a = *(const v8h*)(p + base);
  float v[8];
#pragma unroll
  for (int i = 0; i < 8; ++i) v[i] = (float)a[i];
  float m = -1e30f;
#pragma unroll
  for (int i = 0; i < 8; ++i) m = fmaxf(m, v[i]);
  m = blockMax(m);
  float sum = 0.f;
#pragma unroll
  for (int i = 0; i < 8; ++i) {
    v[i] = exp2f((v[i] - m) * 1.44269504f);
    sum += v[i];
  }
  sum = blockSum(sum);
  const float inv = 1.0f / sum;
  v8h o;
#pragma unroll
  for (int i = 0; i < 8; ++i) o[i] = (_Float16)(v[i] * inv);
  *(v8h*)(p + base) = o;
}

// ---- r = LayerNorm(X + Add) -> X (in place) + fp16 copy rF ----
__global__ __launch_bounds__(256) void ln_res_k(
    float* __restrict__ X, const float* __restrict__ Add,
    const float* __restrict__ g, const float* __restrict__ b,
    _Float16* __restrict__ rF) {
  float* xr = X + (size_t)blockIdx.x * D;
  const float* ar = Add + (size_t)blockIdx.x * D;
  _Float16* rf = rF + (size_t)blockIdx.x * D;
  const int d0 = threadIdx.x * 2;
  const float2 xv = *(const float2*)&xr[d0];
  const float2 av = *(const float2*)&ar[d0];
  const float z0 = xv.x + av.x;
  const float z1 = xv.y + av.y;
  const float mu = blockSum(z0 + z1) * (1.0f / D);
  const float dd0 = z0 - mu, dd1 = z1 - mu;
  const float var = blockSum(dd0 * dd0 + dd1 * dd1) * (1.0f / D);
  const float rs = rsqrtf(var + 1e-5f);
  const float2 gv = *(const float2*)&g[d0];
  const float2 bv = *(const float2*)&b[d0];
  const float v0 = dd0 * rs * gv.x + bv.x;
  const float v1 = dd1 * rs * gv.y + bv.y;
  *(float2*)&xr[d0] = make_float2(v0, v1);
  *(v2h*)&rf[d0] = v2h{(_Float16)v0, (_Float16)v1};
}

// ---- out = LayerNorm(R + F), fp32 ----
__global__ __launch_bounds__(256) void ln_out_k(
    const float* __restrict__ R, const float* __restrict__ F,
    const float* __restrict__ g, const float* __restrict__ b,
    float* __restrict__ out) {
  const float* rr = R + (size_t)blockIdx.x * D;
  const float* fr = F + (size_t)blockIdx.x * D;
  float* orow = out + (size_t)blockIdx.x * D;
  const int d0 = threadIdx.x * 2;
  const float2 rv = *(const float2*)&rr[d0];
  const float2 fv = *(const float2*)&fr[d0];
  const float z0 = rv.x + fv.x;
  const float z1 = rv.y + fv.y;
  const float mu = blockSum(z0 + z1) * (1.0f / D);
  const float dd0 = z0 - mu, dd1 = z1 - mu;
  const float var = blockSum(dd0 * dd0 + dd1 * dd1) * (1.0f / D);
  const float rs = rsqrtf(var + 1e-5f);
  const float2 gv = *(const float2*)&g[d0];
  const float2 bv = *(const float2*)&b[d0];
  *(float2*)&orow[d0] =
      make_float2(dd0 * rs * gv.x + bv.x, dd1 * rs * gv.y + bv.y);
}

extern "C" void kernel_launch(void* const* d_in, const int* in_sizes, int n_in,
                              void* d_out, int out_size, void* d_ws, size_t ws_size,
                              hipStream_t stream) {
  (void)in_sizes; (void)n_in; (void)out_size; (void)ws_size;
  const int*   seq = (const int*)d_in[0];
  const float* emb = (const float*)d_in[1];
  const float* wk  = (const float*)d_in[2];
  const float* bk  = (const float*)d_in[3];
  const float* wq  = (const float*)d_in[4];
  const float* bq  = (const float*)d_in[5];
  const float* wv  = (const float*)d_in[6];
  const float* bv  = (const float*)d_in[7];
  const float* lng = (const float*)d_in[8];
  const float* lnb = (const float*)d_in[9];
  const float* w1  = (const float*)d_in[10];
  const float* b1  = (const float*)d_in[11];
  const float* w2  = (const float*)d_in[12];
  const float* b2  = (const float*)d_in[13];

  // Workspace (MB offsets, lifetimes):
  //  [0,16)    X fp32 (x -> r in-place)
  //  [16,24)   Xh fp16 (dead after QKV)
  //  [24,32)   kF fp16 (dead after scores)  -> rF fp16
  //  [32,40)   qF fp16 (dead after scores)  -> ff fp32 [32,48)
  //  [40,48)   vT fp16 [z][D][S]            (ff tail; vT dead after PV)
  //  [48,80)   Sc fp16, softmax in place (dead after PV) -> hF fp16
  //  [81,97)   attn fp32 (dead after ln_res)
  //  [100,...) wcat 1.5MB, bcat 8KB, w1T 2MB, w2T 2MB
  const size_t MBy = 1024 * 1024;
  char* wsb = (char*)d_ws;
  float*    X    = (float*)wsb;
  _Float16* Xh   = (_Float16*)(wsb + 16 * MBy);
  _Float16* kF   = (_Float16*)(wsb + 24 * MBy);
  _Float16* qF   = (_Float16*)(wsb + 32 * MBy);
  _Float16* vT   = (_Float16*)(wsb + 40 * MBy);
  _Float16* Sc   = (_Float16*)(wsb + 48 * MBy);
  float*    attn = (float*)(wsb + 81 * MBy);
  _Float16* rF   = (_Float16*)(wsb + 24 * MBy);
  _Float16* hF   = (_Float16*)(wsb + 48 * MBy);
  float*    ff   = (float*)(wsb + 32 * MBy);
  _Float16* wcat = (_Float16*)(wsb + 100 * MBy);
  float*    bcat = (float*)(wsb + 102 * MBy);
  _Float16* w1T  = (_Float16*)(wsb + 103 * MBy);
  _Float16* w2T  = (_Float16*)(wsb + 105 * MBy);

  const long SD = (long)S * D, SSl = (long)S * S;

  prep_k<<<11270, 256, 0, stream>>>(wk, wq, wv, w1, w2, bk, bq, bv,
                                    wcat, w1T, w2T, bcat);
  embed_pos_k<<<BS, 256, 0, stream>>>(seq, emb, X, Xh);

  // fused QKV projection: [8192,512] @ wcat^T[512,1536], split epilogue
  mm_k<128, 4, 0><<<dim3(12, 64, 1), 256, 0, stream>>>(
      Xh, wcat, kF, qF, vT, bcat, 1536, D, 0, 0, 0, 1.0f);

  // scores = (k @ q^T)/sqrt(D) -> fp16, batched
  mm_k<128, 1, 0><<<dim3(16, 16, BB), 256, 0, stream>>>(
      kF, qF, Sc, nullptr, nullptr, nullptr, S, D, SD, SD, SSl,
      0.044194173824159216f);

  // softmax in place over Sc
  softmax_k<<<BS, 256, 0, stream>>>(Sc);

  // attn = P @ v (pipelined TM=64, 3-buf 2-deep), batched
  mm64p_k<<<dim3(4, 32, BB), 256, 0, stream>>>(
      Sc, vT, attn, nullptr, D, S, SSl, (long)D * S, SD, 1.0f);

  // r = LN(x + attn) -> X (+ fp16 rF)
  ln_res_k<<<BS, 256, 0, stream>>>(X, attn, lng, lnb, rF);

  // h = gelu(r @ w1 + b1) -> fp16 (fast inline erf)
  mm_k<128, 1, 1><<<dim3(16, 64, 1), 256, 0, stream>>>(
      rF, w1T, hF, nullptr, nullptr, b1, DFF, D, 0, 0, 0, 1.0f);
  // ff = h @ w2 + b2 -> fp32 (pipelined TM=64, 3-buf 2-deep)
  mm64p_k<<<dim3(4, 128, 1), 256, 0, stream>>>(
      hF, w2T, ff, b2, D, DFF, 0, 0, 0, 1.0f);

  // out = LN(r + ff)
  ln_out_k<<<BS, 256, 0, stream>>>(X, ff, lng, lnb, (float*)d_out);
}